// Round 21
// baseline (92.545 us; speedup 1.0000x reference)
//
#include <hip/hip_runtime.h>
#include <hip/hip_bf16.h>

#define NB 4
#define NQ 512
#define NK 2048
#define ND 256
#define NH 64
#define QT 8                      // queries per attn block
#define KSPLIT 8

#define SCALE_C 2.8853900817779268f   // 2*log2(e): exp2(C*x) = e^{2x}
#define L2E     1.4426950408889634f

#define PO_FLOATS ((size_t)NB * NQ * ND)          // 524288
#define ACC_FLOATS (PO_FLOATS + (size_t)NB * NQ)  // + l_acc 2048

__device__ __forceinline__ unsigned short f2b(float f) {   // f32 -> bf16 (RNE)
    unsigned u = __float_as_uint(f);
    u += 0x7fffu + ((u >> 16) & 1u);
    return (unsigned short)(u >> 16);
}
__device__ __forceinline__ float b2f_lo(unsigned u) { return __uint_as_float(u << 16); }
__device__ __forceinline__ float b2f_hi(unsigned u) { return __uint_as_float(u & 0xffff0000u); }

__device__ __forceinline__ float wred_sum(float v) {
#pragma unroll
    for (int off = 32; off; off >>= 1) v += __shfl_xor(v, off, 64);
    return v;
}

// ---------- kernel A: projections -> EXPONENTIALS; also zeroes the accumulators ----------
// queries -> EQ[b*NQ+q][h] = e^{2 q.Wq[h]}; keys -> EK4[(b*16+h/4)*NK + k] h-quad
__global__ __launch_bounds__(256) void proj_kernel(
    const float* __restrict__ queries, const float* __restrict__ keys,
    const float* __restrict__ Wq, const float* __restrict__ Wk,
    float* __restrict__ eq, float4* __restrict__ ek4, float* __restrict__ po_acc)
{
    __shared__ __align__(16) float in_lds[16][256];   // 16 KB; reused as [16][64] out
    const int t = threadIdx.x;
    const int row0 = blockIdx.x * 16;
    const bool isQ = row0 < NB * NQ;

    // zero stripe of po_acc + l_acc (526336 floats over 640 blocks -> 824 each)
    {
        const size_t zb = (size_t)blockIdx.x * 824;
#pragma unroll
        for (int i = 0; i < 4; ++i) {
            int loc = t + i * 256;
            size_t idx = zb + loc;
            if (loc < 824 && idx < ACC_FLOATS) po_acc[idx] = 0.f;
        }
    }

    const float* src = isQ ? (queries + (size_t)row0 * ND)
                           : (keys + (size_t)(row0 - NB * NQ) * ND);
    const float* W = isQ ? Wq : Wk;

    const float4* src4 = (const float4*)src;
#pragma unroll
    for (int i = 0; i < 4; ++i) {
        int f4 = t + 256 * i;
        ((float4*)&in_lds[0][0])[f4] = src4[f4];
    }
    __syncthreads();

    const int w = t >> 6, h = t & 63;
    const int r0 = w * 4;
    float a[4] = {0.f, 0.f, 0.f, 0.f};
#pragma unroll 4
    for (int d4 = 0; d4 < 64; ++d4) {
        const float* Wp = W + (size_t)(d4 * 4) * NH + h;
        float w0 = Wp[0], w1 = Wp[NH], w2 = Wp[2 * NH], w3 = Wp[3 * NH];
#pragma unroll
        for (int i = 0; i < 4; ++i) {
            float4 x = ((const float4*)in_lds[r0 + i])[d4];
            a[i] = fmaf(x.x, w0, fmaf(x.y, w1, fmaf(x.z, w2, fmaf(x.w, w3, a[i]))));
        }
    }
    if (isQ) {
#pragma unroll
        for (int i = 0; i < 4; ++i)
            eq[(size_t)(row0 + r0 + i) * NH + h] =
                __builtin_amdgcn_exp2f(a[i] * SCALE_C);
    } else {
        // transpose through LDS to emit h-quads per key
        __syncthreads();                              // in_lds reads complete
        float* out2 = &in_lds[0][0];                  // [16][64]
#pragma unroll
        for (int i = 0; i < 4; ++i)
            out2[(r0 + i) * 64 + h] = __builtin_amdgcn_exp2f(a[i] * SCALE_C);
        __syncthreads();
        const int row = t >> 4, hb = t & 15;          // 16 rows x 16 h-quads
        float4 v = *(const float4*)&out2[row * 64 + hb * 4];
        int kr = row0 - NB * NQ + row;
        int b = kr >> 11, k = kr & (NK - 1);
        ek4[((size_t)(b * 16 + hb)) * NK + k] = v;
    }
}

// ---------- kernel B: partial scores + no-max softmax + partial PV ----------
// grid = NB*(NQ/QT)*KSPLIT = 2048 blocks, 512 threads (8 waves), 4 blocks/CU
// resident -> 2x oversubscription with refill (fixes makespan imbalance).
// Block decode (diagonal batch<->split pairing): g = n&255, sp = n>>8 (0..7),
//   b = ((g>>6)+sp)&3, qt = g&63.
// Balanced dynamic split: step = roundup64(kveff)>>3 (mult of 8, <= 256);
// phase 1 straight-line one-k-per-thread. Score inner loop: R18's 4-way
// rcp-combine (14 VALU + 1 trans per h-quad). Results flushed by atomicAdd
// into po_acc/l_acc (each cell receives KSPLIT adds).
__global__ __launch_bounds__(512, 8) void attn_part(
    const float* __restrict__ values, const int* __restrict__ valid_lens,
    const float* __restrict__ wv,
    const float* __restrict__ eq, const float4* __restrict__ ek4,
    float* __restrict__ po_acc, float* __restrict__ l_acc)
{
    __shared__ __align__(16) float qp_l[QT][NH];      // 2 KB (EQ tile, LDS broadcast)
    __shared__ __align__(16) float wv2_l[NH];         // -2*wv
    __shared__ float sumwv_l;
    __shared__ __align__(16) float buf[8192];         // 32 KB: p bf16 / red scratch
    __shared__ float red_l[QT][8];

    unsigned short* p_l = (unsigned short*)buf;       // p_l[kl*8 + q], bf16

    const int t = threadIdx.x;
    const int n = blockIdx.x;
    const int g = n & 255;
    const int sp = n >> 8;                            // 0..7
    const int b  = ((g >> 6) + sp) & 3;
    const int qt = g & 63;
    const int q0 = qt * QT;
    const int wid = t >> 6;
    const int dl = (t & 63) * 4;

    if (t < 128) {
        int q = t >> 4, h4 = t & 15;
        ((float4*)qp_l[q])[h4] =
            ((const float4*)(eq + (size_t)(b * NQ + q0 + q) * NH))[h4];
    }
    if (t < 64) {
        float wvv = wv[t];
        wv2_l[t] = -2.0f * wvv;
        float s = wred_sum(wvv);
        if (t == 0) sumwv_l = s;
    }
    int vl = valid_lens[b];
    const int kv = vl < 0 ? 0 : (vl > NK ? NK : vl);
    const int kveff = (kv == 0) ? NK : kv;    // kv==0 -> uniform over all keys
    // balanced bounds, range always multiple of 8 and <= 256
    const int step   = ((kveff + 63) & ~63) >> 3;        // ceil(kveff/8) to mult-of-8
    const int kvr8   = (kveff + 7) & ~7;
    const int kstart = sp * step;
    int kend = kstart + step; if (kend > kvr8) kend = kvr8;
    const int range8 = (kend > kstart) ? (kend - kstart) : 0;   // <= 256
    __syncthreads();
    const float sumwv = sumwv_l;

    // ---- phase 1: e-values (bf16) into p_l, ONE k per thread ----
    {
        const int kl = t;
        float sum_q[QT];
#pragma unroll
        for (int q = 0; q < QT; ++q) sum_q[q] = 0.f;
        if (kl < range8) {
            const int kg = kstart + kl;
            float e[QT];
            if (kv == 0) {
#pragma unroll
                for (int q = 0; q < QT; ++q) e[q] = 1.0f;
            } else if (kg < kv) {
                float s[QT];
#pragma unroll
                for (int q = 0; q < QT; ++q) s[q] = sumwv;
                const float4* kT4 = ek4 + (size_t)(b * 16) * NK + kg;  // h-quad stride NK
#pragma unroll
                for (int gq = 0; gq < 4; ++gq) {      // 4 batches of 4 h-quads
                    float4 kb[4];                     // 4 dwordx4 in flight
#pragma unroll
                    for (int i = 0; i < 4; ++i)
                        kb[i] = kT4[(size_t)(gq * 4 + i) * NK];
#pragma unroll
                    for (int i = 0; i < 4; ++i) {
                        const int h4 = gq * 4 + i;
                        float4 w4 = ((const float4*)wv2_l)[h4];
                        float4 kh = kb[i];
#pragma unroll
                        for (int q = 0; q < QT; ++q) {
                            float4 qh = ((const float4*)qp_l[q])[h4];   // LDS broadcast
                            // 4-way rcp combine: one trans per h-quad
                            float d0 = fmaf(qh.x, kh.x, 1.0f);
                            float d1 = fmaf(qh.y, kh.y, 1.0f);
                            float d2 = fmaf(qh.z, kh.z, 1.0f);
                            float d3 = fmaf(qh.w, kh.w, 1.0f);
                            float d01 = d0 * d1;
                            float d23 = d2 * d3;
                            float n01 = w4.x * d1;
                            n01 = fmaf(w4.y, d0, n01);
                            float n23 = w4.z * d3;
                            n23 = fmaf(w4.w, d2, n23);
                            float num = n01 * d23;
                            num = fmaf(n23, d01, num);
                            float r = __builtin_amdgcn_rcpf(d01 * d23);
                            s[q] = fmaf(num, r, s[q]);
                        }
                    }
                }
#pragma unroll
                for (int q = 0; q < QT; ++q) e[q] = __builtin_amdgcn_exp2f(s[q] * L2E);
            } else {
#pragma unroll
                for (int q = 0; q < QT; ++q) e[q] = 0.f;
            }
            // pack to bf16; sums use rounded values so l matches PV exactly
            unsigned eb[QT];
#pragma unroll
            for (int q = 0; q < QT; ++q) {
                eb[q] = (unsigned)f2b(e[q]);
                sum_q[q] = b2f_lo(eb[q]);
            }
            uint4 u;
            u.x = eb[0] | (eb[1] << 16);
            u.y = eb[2] | (eb[3] << 16);
            u.z = eb[4] | (eb[5] << 16);
            u.w = eb[6] | (eb[7] << 16);
            *(uint4*)&p_l[(size_t)kl * 8] = u;
        }
#pragma unroll
        for (int q = 0; q < QT; ++q) {
            float s = wred_sum(sum_q[q]);
            if ((t & 63) == 0) red_l[q][wid] = s;
        }
    }
    __syncthreads();

    // ---- phase 2: PV, waves split k (row kl handled by wave kl%8) ----
    float4 acc[QT];
#pragma unroll
    for (int q = 0; q < QT; ++q) acc[q] = make_float4(0.f, 0.f, 0.f, 0.f);

    const float* Vb = values + ((size_t)b * NK + kstart) * ND;
#pragma unroll 2
    for (int kl = wid; kl < range8; kl += 8) {
        uint4 u = *(const uint4*)&p_l[(size_t)kl * 8];   // 1 b128 = all 8 bf16 p's
        float pr0 = b2f_lo(u.x), pr1 = b2f_hi(u.x);
        float pr2 = b2f_lo(u.y), pr3 = b2f_hi(u.y);
        float pr4 = b2f_lo(u.z), pr5 = b2f_hi(u.z);
        float pr6 = b2f_lo(u.w), pr7 = b2f_hi(u.w);
        float4 v = *(const float4*)(Vb + (size_t)kl * ND + dl);  // coalesced 1KB
        acc[0].x = fmaf(pr0, v.x, acc[0].x); acc[0].y = fmaf(pr0, v.y, acc[0].y);
        acc[0].z = fmaf(pr0, v.z, acc[0].z); acc[0].w = fmaf(pr0, v.w, acc[0].w);
        acc[1].x = fmaf(pr1, v.x, acc[1].x); acc[1].y = fmaf(pr1, v.y, acc[1].y);
        acc[1].z = fmaf(pr1, v.z, acc[1].z); acc[1].w = fmaf(pr1, v.w, acc[1].w);
        acc[2].x = fmaf(pr2, v.x, acc[2].x); acc[2].y = fmaf(pr2, v.y, acc[2].y);
        acc[2].z = fmaf(pr2, v.z, acc[2].z); acc[2].w = fmaf(pr2, v.w, acc[2].w);
        acc[3].x = fmaf(pr3, v.x, acc[3].x); acc[3].y = fmaf(pr3, v.y, acc[3].y);
        acc[3].z = fmaf(pr3, v.z, acc[3].z); acc[3].w = fmaf(pr3, v.w, acc[3].w);
        acc[4].x = fmaf(pr4, v.x, acc[4].x); acc[4].y = fmaf(pr4, v.y, acc[4].y);
        acc[4].z = fmaf(pr4, v.z, acc[4].z); acc[4].w = fmaf(pr4, v.w, acc[4].w);
        acc[5].x = fmaf(pr5, v.x, acc[5].x); acc[5].y = fmaf(pr5, v.y, acc[5].y);
        acc[5].z = fmaf(pr5, v.z, acc[5].z); acc[5].w = fmaf(pr5, v.w, acc[5].w);
        acc[6].x = fmaf(pr6, v.x, acc[6].x); acc[6].y = fmaf(pr6, v.y, acc[6].y);
        acc[6].z = fmaf(pr6, v.z, acc[6].z); acc[6].w = fmaf(pr6, v.w, acc[6].w);
        acc[7].x = fmaf(pr7, v.x, acc[7].x); acc[7].y = fmaf(pr7, v.y, acc[7].y);
        acc[7].z = fmaf(pr7, v.z, acc[7].z); acc[7].w = fmaf(pr7, v.w, acc[7].w);
    }
    __syncthreads();                          // p-values dead -> reuse buf as scratch

    // ---- phase 3: tree-reduce partials across waves (8 -> 4 -> 2 -> 1) ----
    if (wid >= 4) {
        float* s = buf + (size_t)(wid - 4) * 2048;
#pragma unroll
        for (int q = 0; q < QT; ++q) *(float4*)(s + q * 256 + dl) = acc[q];
    }
    __syncthreads();
    if (wid < 4) {
        const float* s = buf + (size_t)wid * 2048;
#pragma unroll
        for (int q = 0; q < QT; ++q) {
            float4 r = *(const float4*)(s + q * 256 + dl);
            acc[q].x += r.x; acc[q].y += r.y; acc[q].z += r.z; acc[q].w += r.w;
        }
    }
    __syncthreads();
    if (wid >= 2 && wid < 4) {
        float* s = buf + (size_t)(wid - 2) * 2048;
#pragma unroll
        for (int q = 0; q < QT; ++q) *(float4*)(s + q * 256 + dl) = acc[q];
    }
    __syncthreads();
    if (wid < 2) {
        const float* s = buf + (size_t)wid * 2048;
#pragma unroll
        for (int q = 0; q < QT; ++q) {
            float4 r = *(const float4*)(s + q * 256 + dl);
            acc[q].x += r.x; acc[q].y += r.y; acc[q].z += r.z; acc[q].w += r.w;
        }
    }
    __syncthreads();
    if (wid == 1) {
#pragma unroll
        for (int q = 0; q < QT; ++q) *(float4*)(buf + q * 256 + dl) = acc[q];
    }
    __syncthreads();
    if (wid == 0) {
#pragma unroll
        for (int q = 0; q < QT; ++q) {
            float4 r = *(const float4*)(buf + q * 256 + dl);
            acc[q].x += r.x; acc[q].y += r.y; acc[q].z += r.z; acc[q].w += r.w;
            float* base = &po_acc[((size_t)(b * NQ + q0 + q)) * ND + dl];
            atomicAdd(base + 0, acc[q].x);
            atomicAdd(base + 1, acc[q].y);
            atomicAdd(base + 2, acc[q].z);
            atomicAdd(base + 3, acc[q].w);
        }
        if (t < QT) {
            float l = 0.f;
#pragma unroll
            for (int i = 0; i < 8; ++i) l += red_l[t][i];
            if (l != 0.f) atomicAdd(&l_acc[b * NQ + q0 + t], l);
        }
    }
}

// ---------- kernel C: normalize ----------
__global__ __launch_bounds__(256) void combine_kernel(
    const float* __restrict__ po_acc, const float* __restrict__ l_acc,
    float* __restrict__ out)
{
    const int t = threadIdx.x;
    const int row = blockIdx.x * 4 + (t >> 6);
    const int dl = (t & 63) * 4;
    const float inv = 1.0f / l_acc[row];
    float4 p = *(const float4*)(po_acc + (size_t)row * ND + dl);
    float4 o = make_float4(p.x * inv, p.y * inv, p.z * inv, p.w * inv);
    *(float4*)(out + (size_t)row * ND + dl) = o;
}

extern "C" void kernel_launch(void* const* d_in, const int* in_sizes, int n_in,
                              void* d_out, int out_size, void* d_ws, size_t ws_size,
                              hipStream_t stream) {
    const float* queries   = (const float*)d_in[0];
    const float* keys      = (const float*)d_in[1];
    const float* values    = (const float*)d_in[2];
    const int* valid_lens  = (const int*)d_in[3];
    const float* Wq        = (const float*)d_in[4];
    const float* Wk        = (const float*)d_in[5];
    const float* wv        = (const float*)d_in[6];
    float* out = (float*)d_out;

    float* eq     = (float*)d_ws;                          // NB*NQ*NH     (0.5 MB)
    float4* ek4   = (float4*)(eq + (size_t)NB * NQ * NH);  // NB*16*NK f4  (2 MB)
    float* po_acc = (float*)(ek4 + (size_t)NB * 16 * NK);  // NB*NQ*ND     (2 MB)
    float* l_acc  = po_acc + PO_FLOATS;                    // NB*NQ

    proj_kernel<<<(NB * NQ + NB * NK) / 16, 256, 0, stream>>>(queries, keys, Wq, Wk, eq, ek4, po_acc);
    attn_part<<<NB * (NQ / QT) * KSPLIT, 512, 0, stream>>>(values, valid_lens, wv, eq, ek4, po_acc, l_acc);
    combine_kernel<<<NB * NQ / 4, 256, 0, stream>>>(po_acc, l_acc, out);
}

// Round 22
// 66.407 us; speedup vs baseline: 1.3936x; 1.3936x over previous
//
#include <hip/hip_runtime.h>
#include <hip/hip_bf16.h>

#define NB 4
#define NQ 512
#define NK 2048
#define ND 256
#define NH 64
#define QT 8                      // queries per attn block
#define KSPLIT 8

#define SCALE_C 2.8853900817779268f   // 2*log2(e): exp2(C*x) = e^{2x}
#define L2E     1.4426950408889634f

__device__ __forceinline__ unsigned short f2b(float f) {   // f32 -> bf16 (RNE)
    unsigned u = __float_as_uint(f);
    u += 0x7fffu + ((u >> 16) & 1u);
    return (unsigned short)(u >> 16);
}
__device__ __forceinline__ float b2f_lo(unsigned u) { return __uint_as_float(u << 16); }
__device__ __forceinline__ float b2f_hi(unsigned u) { return __uint_as_float(u & 0xffff0000u); }

__device__ __forceinline__ float wred_sum(float v) {
#pragma unroll
    for (int off = 32; off; off >>= 1) v += __shfl_xor(v, off, 64);
    return v;
}

// ---------- kernel A: projections -> EXPONENTIALS of 2x the projection ----------
// queries -> EQ[b*NQ+q][h] = e^{2 q.Wq[h]}   (row-major)
// keys    -> EK4[(b*16 + h/4)*NK + k] : float4 h-quad of e^{2 k.Wk[h]}
__global__ __launch_bounds__(256) void proj_kernel(
    const float* __restrict__ queries, const float* __restrict__ keys,
    const float* __restrict__ Wq, const float* __restrict__ Wk,
    float* __restrict__ eq, float4* __restrict__ ek4)
{
    __shared__ __align__(16) float in_lds[16][256];   // 16 KB; reused as [16][64] out
    const int t = threadIdx.x;
    const int row0 = blockIdx.x * 16;
    const bool isQ = row0 < NB * NQ;                  // blocks are purely Q or purely K
    const float* src = isQ ? (queries + (size_t)row0 * ND)
                           : (keys + (size_t)(row0 - NB * NQ) * ND);
    const float* W = isQ ? Wq : Wk;

    const float4* src4 = (const float4*)src;
#pragma unroll
    for (int i = 0; i < 4; ++i) {
        int f4 = t + 256 * i;
        ((float4*)&in_lds[0][0])[f4] = src4[f4];
    }
    __syncthreads();

    const int w = t >> 6, h = t & 63;
    const int r0 = w * 4;
    float a[4] = {0.f, 0.f, 0.f, 0.f};
#pragma unroll 4
    for (int d4 = 0; d4 < 64; ++d4) {
        const float* Wp = W + (size_t)(d4 * 4) * NH + h;
        float w0 = Wp[0], w1 = Wp[NH], w2 = Wp[2 * NH], w3 = Wp[3 * NH];
#pragma unroll
        for (int i = 0; i < 4; ++i) {
            float4 x = ((const float4*)in_lds[r0 + i])[d4];
            a[i] = fmaf(x.x, w0, fmaf(x.y, w1, fmaf(x.z, w2, fmaf(x.w, w3, a[i]))));
        }
    }
    if (isQ) {
#pragma unroll
        for (int i = 0; i < 4; ++i)
            eq[(size_t)(row0 + r0 + i) * NH + h] =
                __builtin_amdgcn_exp2f(a[i] * SCALE_C);
    } else {
        // transpose through LDS to emit h-quads per key
        __syncthreads();                              // in_lds reads complete
        float* out2 = &in_lds[0][0];                  // [16][64]
#pragma unroll
        for (int i = 0; i < 4; ++i)
            out2[(r0 + i) * 64 + h] = __builtin_amdgcn_exp2f(a[i] * SCALE_C);
        __syncthreads();
        const int row = t >> 4, hb = t & 15;          // 16 rows x 16 h-quads
        float4 v = *(const float4*)&out2[row * 64 + hb * 4];
        int kr = row0 - NB * NQ + row;
        int b = kr >> 11, k = kr & (NK - 1);
        ek4[((size_t)(b * 16 + hb)) * NK + k] = v;
    }
}

// ---------- kernel B: partial scores + no-max softmax + partial PV ----------
// grid = NB*(NQ/QT)*KSPLIT = 2048 blocks, 512 threads (8 waves), 4 blocks/CU
// resident -> 2x oversubscription WITH REFILL (attacks makespan imbalance).
// Block decode (diagonal batch<->split pairing): g = n&255, sp = n>>8 (0..7),
//   b = ((g>>6)+sp)&3, qt = g&63.
// Balanced dynamic split: step = roundup64(kveff)>>3 (mult of 8, <= 256);
// phase 1 straight-line one-k-per-thread. Score: R18 4-way rcp-combine.
// Partials go to po[row*KSPLIT+sp] / pml via PLAIN stores (no atomics).
__global__ __launch_bounds__(512, 8) void attn_part(
    const float* __restrict__ values, const int* __restrict__ valid_lens,
    const float* __restrict__ wv,
    const float* __restrict__ eq, const float4* __restrict__ ek4,
    float* __restrict__ po, float* __restrict__ pml)
{
    __shared__ __align__(16) float qp_l[QT][NH];      // 2 KB (EQ tile, LDS broadcast)
    __shared__ __align__(16) float wv2_l[NH];         // -2*wv
    __shared__ float sumwv_l;
    __shared__ __align__(16) float buf[8192];         // 32 KB: p bf16 / red scratch
    __shared__ float red_l[QT][8];

    unsigned short* p_l = (unsigned short*)buf;       // p_l[kl*8 + q], bf16

    const int t = threadIdx.x;
    const int n = blockIdx.x;
    const int g = n & 255;
    const int sp = n >> 8;                            // 0..7
    const int b  = ((g >> 6) + sp) & 3;
    const int qt = g & 63;
    const int q0 = qt * QT;
    const int wid = t >> 6;
    const int dl = (t & 63) * 4;

    if (t < 128) {
        int q = t >> 4, h4 = t & 15;
        ((float4*)qp_l[q])[h4] =
            ((const float4*)(eq + (size_t)(b * NQ + q0 + q) * NH))[h4];
    }
    if (t < 64) {
        float wvv = wv[t];
        wv2_l[t] = -2.0f * wvv;
        float s = wred_sum(wvv);
        if (t == 0) sumwv_l = s;
    }
    int vl = valid_lens[b];
    const int kv = vl < 0 ? 0 : (vl > NK ? NK : vl);
    const int kveff = (kv == 0) ? NK : kv;    // kv==0 -> uniform over all keys
    // balanced bounds, range always multiple of 8 and <= 256
    const int step   = ((kveff + 63) & ~63) >> 3;        // ceil(kveff/8) to mult-of-8
    const int kvr8   = (kveff + 7) & ~7;
    const int kstart = sp * step;
    int kend = kstart + step; if (kend > kvr8) kend = kvr8;
    const int range8 = (kend > kstart) ? (kend - kstart) : 0;   // <= 256
    __syncthreads();
    const float sumwv = sumwv_l;

    // ---- phase 1: e-values (bf16) into p_l, ONE k per thread ----
    {
        const int kl = t;
        float sum_q[QT];
#pragma unroll
        for (int q = 0; q < QT; ++q) sum_q[q] = 0.f;
        if (kl < range8) {
            const int kg = kstart + kl;
            float e[QT];
            if (kv == 0) {
#pragma unroll
                for (int q = 0; q < QT; ++q) e[q] = 1.0f;
            } else if (kg < kv) {
                float s[QT];
#pragma unroll
                for (int q = 0; q < QT; ++q) s[q] = sumwv;
                const float4* kT4 = ek4 + (size_t)(b * 16) * NK + kg;  // h-quad stride NK
#pragma unroll
                for (int gq = 0; gq < 4; ++gq) {      // 4 batches of 4 h-quads
                    float4 kb[4];                     // 4 dwordx4 in flight
#pragma unroll
                    for (int i = 0; i < 4; ++i)
                        kb[i] = kT4[(size_t)(gq * 4 + i) * NK];
#pragma unroll
                    for (int i = 0; i < 4; ++i) {
                        const int h4 = gq * 4 + i;
                        float4 w4 = ((const float4*)wv2_l)[h4];
                        float4 kh = kb[i];
#pragma unroll
                        for (int q = 0; q < QT; ++q) {
                            float4 qh = ((const float4*)qp_l[q])[h4];   // LDS broadcast
                            // 4-way rcp combine: one trans per h-quad
                            float d0 = fmaf(qh.x, kh.x, 1.0f);
                            float d1 = fmaf(qh.y, kh.y, 1.0f);
                            float d2 = fmaf(qh.z, kh.z, 1.0f);
                            float d3 = fmaf(qh.w, kh.w, 1.0f);
                            float d01 = d0 * d1;
                            float d23 = d2 * d3;
                            float n01 = w4.x * d1;
                            n01 = fmaf(w4.y, d0, n01);
                            float n23 = w4.z * d3;
                            n23 = fmaf(w4.w, d2, n23);
                            float num = n01 * d23;
                            num = fmaf(n23, d01, num);
                            float r = __builtin_amdgcn_rcpf(d01 * d23);
                            s[q] = fmaf(num, r, s[q]);
                        }
                    }
                }
#pragma unroll
                for (int q = 0; q < QT; ++q) e[q] = __builtin_amdgcn_exp2f(s[q] * L2E);
            } else {
#pragma unroll
                for (int q = 0; q < QT; ++q) e[q] = 0.f;
            }
            // pack to bf16; sums use rounded values so l matches PV exactly
            unsigned eb[QT];
#pragma unroll
            for (int q = 0; q < QT; ++q) {
                eb[q] = (unsigned)f2b(e[q]);
                sum_q[q] = b2f_lo(eb[q]);
            }
            uint4 u;
            u.x = eb[0] | (eb[1] << 16);
            u.y = eb[2] | (eb[3] << 16);
            u.z = eb[4] | (eb[5] << 16);
            u.w = eb[6] | (eb[7] << 16);
            *(uint4*)&p_l[(size_t)kl * 8] = u;
        }
#pragma unroll
        for (int q = 0; q < QT; ++q) {
            float s = wred_sum(sum_q[q]);
            if ((t & 63) == 0) red_l[q][wid] = s;
        }
    }
    __syncthreads();

    // ---- phase 2: PV, waves split k (row kl handled by wave kl%8) ----
    float4 acc[QT];
#pragma unroll
    for (int q = 0; q < QT; ++q) acc[q] = make_float4(0.f, 0.f, 0.f, 0.f);

    const float* Vb = values + ((size_t)b * NK + kstart) * ND;
#pragma unroll 2
    for (int kl = wid; kl < range8; kl += 8) {
        uint4 u = *(const uint4*)&p_l[(size_t)kl * 8];   // 1 b128 = all 8 bf16 p's
        float pr0 = b2f_lo(u.x), pr1 = b2f_hi(u.x);
        float pr2 = b2f_lo(u.y), pr3 = b2f_hi(u.y);
        float pr4 = b2f_lo(u.z), pr5 = b2f_hi(u.z);
        float pr6 = b2f_lo(u.w), pr7 = b2f_hi(u.w);
        float4 v = *(const float4*)(Vb + (size_t)kl * ND + dl);  // coalesced 1KB
        acc[0].x = fmaf(pr0, v.x, acc[0].x); acc[0].y = fmaf(pr0, v.y, acc[0].y);
        acc[0].z = fmaf(pr0, v.z, acc[0].z); acc[0].w = fmaf(pr0, v.w, acc[0].w);
        acc[1].x = fmaf(pr1, v.x, acc[1].x); acc[1].y = fmaf(pr1, v.y, acc[1].y);
        acc[1].z = fmaf(pr1, v.z, acc[1].z); acc[1].w = fmaf(pr1, v.w, acc[1].w);
        acc[2].x = fmaf(pr2, v.x, acc[2].x); acc[2].y = fmaf(pr2, v.y, acc[2].y);
        acc[2].z = fmaf(pr2, v.z, acc[2].z); acc[2].w = fmaf(pr2, v.w, acc[2].w);
        acc[3].x = fmaf(pr3, v.x, acc[3].x); acc[3].y = fmaf(pr3, v.y, acc[3].y);
        acc[3].z = fmaf(pr3, v.z, acc[3].z); acc[3].w = fmaf(pr3, v.w, acc[3].w);
        acc[4].x = fmaf(pr4, v.x, acc[4].x); acc[4].y = fmaf(pr4, v.y, acc[4].y);
        acc[4].z = fmaf(pr4, v.z, acc[4].z); acc[4].w = fmaf(pr4, v.w, acc[4].w);
        acc[5].x = fmaf(pr5, v.x, acc[5].x); acc[5].y = fmaf(pr5, v.y, acc[5].y);
        acc[5].z = fmaf(pr5, v.z, acc[5].z); acc[5].w = fmaf(pr5, v.w, acc[5].w);
        acc[6].x = fmaf(pr6, v.x, acc[6].x); acc[6].y = fmaf(pr6, v.y, acc[6].y);
        acc[6].z = fmaf(pr6, v.z, acc[6].z); acc[6].w = fmaf(pr6, v.w, acc[6].w);
        acc[7].x = fmaf(pr7, v.x, acc[7].x); acc[7].y = fmaf(pr7, v.y, acc[7].y);
        acc[7].z = fmaf(pr7, v.z, acc[7].z); acc[7].w = fmaf(pr7, v.w, acc[7].w);
    }
    __syncthreads();                          // p-values dead -> reuse buf as scratch

    // ---- phase 3: tree-reduce partials across waves (8 -> 4 -> 2 -> 1) ----
    if (wid >= 4) {
        float* s = buf + (size_t)(wid - 4) * 2048;
#pragma unroll
        for (int q = 0; q < QT; ++q) *(float4*)(s + q * 256 + dl) = acc[q];
    }
    __syncthreads();
    if (wid < 4) {
        const float* s = buf + (size_t)wid * 2048;
#pragma unroll
        for (int q = 0; q < QT; ++q) {
            float4 r = *(const float4*)(s + q * 256 + dl);
            acc[q].x += r.x; acc[q].y += r.y; acc[q].z += r.z; acc[q].w += r.w;
        }
    }
    __syncthreads();
    if (wid >= 2 && wid < 4) {
        float* s = buf + (size_t)(wid - 2) * 2048;
#pragma unroll
        for (int q = 0; q < QT; ++q) *(float4*)(s + q * 256 + dl) = acc[q];
    }
    __syncthreads();
    if (wid < 2) {
        const float* s = buf + (size_t)wid * 2048;
#pragma unroll
        for (int q = 0; q < QT; ++q) {
            float4 r = *(const float4*)(s + q * 256 + dl);
            acc[q].x += r.x; acc[q].y += r.y; acc[q].z += r.z; acc[q].w += r.w;
        }
    }
    __syncthreads();
    if (wid == 1) {
#pragma unroll
        for (int q = 0; q < QT; ++q) *(float4*)(buf + q * 256 + dl) = acc[q];
    }
    __syncthreads();
    if (wid == 0) {
#pragma unroll
        for (int q = 0; q < QT; ++q) {
            float4 r = *(const float4*)(buf + q * 256 + dl);
            acc[q].x += r.x; acc[q].y += r.y; acc[q].z += r.z; acc[q].w += r.w;
            const size_t row8 = ((size_t)(b * NQ + q0 + q) * KSPLIT + sp);
            *(float4*)(po + row8 * ND + dl) = acc[q];
        }
        if (t < QT) {
            float l = 0.f;
#pragma unroll
            for (int i = 0; i < 8; ++i) l += red_l[t][i];
            pml[((size_t)(b * NQ + q0 + t) * KSPLIT + sp)] = l;
        }
    }
}

// ---------- kernel C: combine the eight splits ----------
__global__ __launch_bounds__(256) void combine_kernel(
    const float* __restrict__ po, const float* __restrict__ pml,
    float* __restrict__ out)
{
    const int t = threadIdx.x;
    const int row = blockIdx.x * 4 + (t >> 6);
    const int dl = (t & 63) * 4;
    float l = 0.f;
#pragma unroll
    for (int s = 0; s < KSPLIT; ++s) l += pml[row * KSPLIT + s];
    float4 o = make_float4(0.f, 0.f, 0.f, 0.f);
#pragma unroll
    for (int s = 0; s < KSPLIT; ++s) {
        float4 p = *(const float4*)(po + ((size_t)row * KSPLIT + s) * ND + dl);
        o.x += p.x; o.y += p.y; o.z += p.z; o.w += p.w;
    }
    const float inv = 1.0f / l;
    o.x *= inv; o.y *= inv; o.z *= inv; o.w *= inv;
    *(float4*)(out + (size_t)row * ND + dl) = o;
}

extern "C" void kernel_launch(void* const* d_in, const int* in_sizes, int n_in,
                              void* d_out, int out_size, void* d_ws, size_t ws_size,
                              hipStream_t stream) {
    const float* queries   = (const float*)d_in[0];
    const float* keys      = (const float*)d_in[1];
    const float* values    = (const float*)d_in[2];
    const int* valid_lens  = (const int*)d_in[3];
    const float* Wq        = (const float*)d_in[4];
    const float* Wk        = (const float*)d_in[5];
    const float* wv        = (const float*)d_in[6];
    float* out = (float*)d_out;

    float* eq   = (float*)d_ws;                         // NB*NQ*NH      (0.5 MB)
    float4* ek4 = (float4*)(eq + (size_t)NB * NQ * NH); // NB*16*NK f4   (2 MB)
    float* po   = (float*)(ek4 + (size_t)NB * 16 * NK); // NB*NQ*8*ND    (16 MB)
    float* pml  = po + (size_t)NB * NQ * KSPLIT * ND;   // NB*NQ*8

    proj_kernel<<<(NB * NQ + NB * NK) / 16, 256, 0, stream>>>(queries, keys, Wq, Wk, eq, ek4);
    attn_part<<<NB * (NQ / QT) * KSPLIT, 512, 0, stream>>>(values, valid_lens, wv, eq, ek4, po, pml);
    combine_kernel<<<NB * NQ / 4, 256, 0, stream>>>(po, pml, out);
}

// Round 23
// 58.209 us; speedup vs baseline: 1.5899x; 1.1408x over previous
//
#include <hip/hip_runtime.h>
#include <hip/hip_bf16.h>

#define NB 4
#define NQ 512
#define NK 2048
#define ND 256
#define NH 64
#define QT 8                      // queries per attn block
#define KSPLIT 4

#define SCALE_C 2.8853900817779268f   // 2*log2(e): exp2(C*x) = e^{2x}
#define L2E     1.4426950408889634f

__device__ __forceinline__ unsigned short f2b(float f) {   // f32 -> bf16 (RNE)
    unsigned u = __float_as_uint(f);
    u += 0x7fffu + ((u >> 16) & 1u);
    return (unsigned short)(u >> 16);
}
__device__ __forceinline__ float b2f_lo(unsigned u) { return __uint_as_float(u << 16); }
__device__ __forceinline__ float b2f_hi(unsigned u) { return __uint_as_float(u & 0xffff0000u); }

__device__ __forceinline__ float wred_sum(float v) {
#pragma unroll
    for (int off = 32; off; off >>= 1) v += __shfl_xor(v, off, 64);
    return v;
}

// ---------- kernel A: projections -> EXPONENTIALS of 2x the projection ----------
// queries -> EQ[b*NQ+q][h] = e^{2 q.Wq[h]}   (row-major)
// keys    -> EK4[(b*16 + h/4)*NK + k] : float4 h-quad of e^{2 k.Wk[h]}
__global__ __launch_bounds__(256) void proj_kernel(
    const float* __restrict__ queries, const float* __restrict__ keys,
    const float* __restrict__ Wq, const float* __restrict__ Wk,
    float* __restrict__ eq, float4* __restrict__ ek4)
{
    __shared__ __align__(16) float in_lds[16][256];   // 16 KB; reused as [16][64] out
    const int t = threadIdx.x;
    const int row0 = blockIdx.x * 16;
    const bool isQ = row0 < NB * NQ;                  // blocks are purely Q or purely K
    const float* src = isQ ? (queries + (size_t)row0 * ND)
                           : (keys + (size_t)(row0 - NB * NQ) * ND);
    const float* W = isQ ? Wq : Wk;

    const float4* src4 = (const float4*)src;
#pragma unroll
    for (int i = 0; i < 4; ++i) {
        int f4 = t + 256 * i;
        ((float4*)&in_lds[0][0])[f4] = src4[f4];
    }
    __syncthreads();

    const int w = t >> 6, h = t & 63;
    const int r0 = w * 4;
    float a[4] = {0.f, 0.f, 0.f, 0.f};
#pragma unroll 4
    for (int d4 = 0; d4 < 64; ++d4) {
        const float* Wp = W + (size_t)(d4 * 4) * NH + h;
        float w0 = Wp[0], w1 = Wp[NH], w2 = Wp[2 * NH], w3 = Wp[3 * NH];
#pragma unroll
        for (int i = 0; i < 4; ++i) {
            float4 x = ((const float4*)in_lds[r0 + i])[d4];
            a[i] = fmaf(x.x, w0, fmaf(x.y, w1, fmaf(x.z, w2, fmaf(x.w, w3, a[i]))));
        }
    }
    if (isQ) {
#pragma unroll
        for (int i = 0; i < 4; ++i)
            eq[(size_t)(row0 + r0 + i) * NH + h] =
                __builtin_amdgcn_exp2f(a[i] * SCALE_C);
    } else {
        // transpose through LDS to emit h-quads per key
        __syncthreads();                              // in_lds reads complete
        float* out2 = &in_lds[0][0];                  // [16][64]
#pragma unroll
        for (int i = 0; i < 4; ++i)
            out2[(r0 + i) * 64 + h] = __builtin_amdgcn_exp2f(a[i] * SCALE_C);
        __syncthreads();
        const int row = t >> 4, hb = t & 15;          // 16 rows x 16 h-quads
        float4 v = *(const float4*)&out2[row * 64 + hb * 4];
        int kr = row0 - NB * NQ + row;
        int b = kr >> 11, k = kr & (NK - 1);
        ek4[((size_t)(b * 16 + hb)) * NK + k] = v;
    }
}

// ---------- kernel B: partial scores + no-max softmax + partial PV ----------
// grid = NB*(NQ/QT)*KSPLIT = 1024 blocks, 512 threads (8 waves).
// Block decode (diagonal batch<->split pairing): g = n&255, sp = n>>8,
//   b = ((g>>6)+sp)&3, qt = g&63.
// Balanced dynamic split (R8 formula): range <= 512, multiple of 8; phase 1
// straight-line one-k-per-thread. Score inner loop: 4-way rcp-combine over
// each h-quad (d_i = 1+EQ*EK > 1, no cancellation):
//   sum_i wv_i/d_i = [ (wv0*d1+wv1*d0)*d2*d3 + (wv2*d3+wv3*d2)*d0*d1 ]
//                    / (d0*d1*d2*d3)          -> 14 VALU + 1 trans / quad
__global__ __launch_bounds__(512, 8) void attn_part(
    const float* __restrict__ values, const int* __restrict__ valid_lens,
    const float* __restrict__ wv,
    const float* __restrict__ eq, const float4* __restrict__ ek4,
    float* __restrict__ po, float* __restrict__ pml)
{
    __shared__ __align__(16) float qp_l[QT][NH];      // 2 KB (EQ tile, LDS broadcast)
    __shared__ __align__(16) float wv2_l[NH];         // -2*wv
    __shared__ float sumwv_l;
    __shared__ __align__(16) float buf[8192];         // 32 KB: p bf16 (8KB) / red scratch
    __shared__ float red_l[QT][8];

    unsigned short* p_l = (unsigned short*)buf;       // p_l[kl*8 + q], bf16

    const int t = threadIdx.x;
    const int n = blockIdx.x;
    const int g = n & 255;
    const int sp = n >> 8;
    const int b  = ((g >> 6) + sp) & 3;
    const int qt = g & 63;
    const int q0 = qt * QT;
    const int wid = t >> 6;
    const int dl = (t & 63) * 4;

    if (t < 128) {
        int q = t >> 4, h4 = t & 15;
        ((float4*)qp_l[q])[h4] =
            ((const float4*)(eq + (size_t)(b * NQ + q0 + q) * NH))[h4];
    }
    if (t < 64) {
        float wvv = wv[t];
        wv2_l[t] = -2.0f * wvv;
        float s = wred_sum(wvv);
        if (t == 0) sumwv_l = s;
    }
    int vl = valid_lens[b];
    const int kv = vl < 0 ? 0 : (vl > NK ? NK : vl);
    const int kveff = (kv == 0) ? NK : kv;    // kv==0 -> uniform over all keys
    // balanced bounds, range always multiple of 8 and <= 512
    const int step   = ((kveff + 31) & ~31) >> 2;        // ceil(kveff/4) to mult-of-8
    const int kvr8   = (kveff + 7) & ~7;
    const int kstart = sp * step;
    int kend = kstart + step; if (kend > kvr8) kend = kvr8;
    const int range8 = (kend > kstart) ? (kend - kstart) : 0;   // <= 512
    __syncthreads();
    const float sumwv = sumwv_l;

    // ---- phase 1: e-values (bf16) into p_l, ONE k per thread ----
    {
        const int kl = t;
        float sum_q[QT];
#pragma unroll
        for (int q = 0; q < QT; ++q) sum_q[q] = 0.f;
        if (kl < range8) {
            const int kg = kstart + kl;
            float e[QT];
            if (kv == 0) {
#pragma unroll
                for (int q = 0; q < QT; ++q) e[q] = 1.0f;
            } else if (kg < kv) {
                float s[QT];
#pragma unroll
                for (int q = 0; q < QT; ++q) s[q] = sumwv;
                const float4* kT4 = ek4 + (size_t)(b * 16) * NK + kg;  // h-quad stride NK
#pragma unroll
                for (int gq = 0; gq < 4; ++gq) {      // 4 batches of 4 h-quads
                    float4 kb[4];                     // 4 dwordx4 in flight
#pragma unroll
                    for (int i = 0; i < 4; ++i)
                        kb[i] = kT4[(size_t)(gq * 4 + i) * NK];
#pragma unroll
                    for (int i = 0; i < 4; ++i) {
                        const int h4 = gq * 4 + i;
                        float4 w4 = ((const float4*)wv2_l)[h4];
                        float4 kh = kb[i];
#pragma unroll
                        for (int q = 0; q < QT; ++q) {
                            float4 qh = ((const float4*)qp_l[q])[h4];   // LDS broadcast
                            // 4-way rcp combine: one trans per h-quad
                            float d0 = fmaf(qh.x, kh.x, 1.0f);
                            float d1 = fmaf(qh.y, kh.y, 1.0f);
                            float d2 = fmaf(qh.z, kh.z, 1.0f);
                            float d3 = fmaf(qh.w, kh.w, 1.0f);
                            float d01 = d0 * d1;
                            float d23 = d2 * d3;
                            float n01 = w4.x * d1;
                            n01 = fmaf(w4.y, d0, n01);
                            float n23 = w4.z * d3;
                            n23 = fmaf(w4.w, d2, n23);
                            float num = n01 * d23;
                            num = fmaf(n23, d01, num);
                            float r = __builtin_amdgcn_rcpf(d01 * d23);
                            s[q] = fmaf(num, r, s[q]);
                        }
                    }
                }
#pragma unroll
                for (int q = 0; q < QT; ++q) e[q] = __builtin_amdgcn_exp2f(s[q] * L2E);
            } else {
#pragma unroll
                for (int q = 0; q < QT; ++q) e[q] = 0.f;
            }
            // pack to bf16; sums use rounded values so l matches PV exactly
            unsigned eb[QT];
#pragma unroll
            for (int q = 0; q < QT; ++q) {
                eb[q] = (unsigned)f2b(e[q]);
                sum_q[q] = b2f_lo(eb[q]);
            }
            uint4 u;
            u.x = eb[0] | (eb[1] << 16);
            u.y = eb[2] | (eb[3] << 16);
            u.z = eb[4] | (eb[5] << 16);
            u.w = eb[6] | (eb[7] << 16);
            *(uint4*)&p_l[(size_t)kl * 8] = u;
        }
#pragma unroll
        for (int q = 0; q < QT; ++q) {
            float s = wred_sum(sum_q[q]);
            if ((t & 63) == 0) red_l[q][wid] = s;
        }
    }
    __syncthreads();

    // ---- phase 2: PV, waves split k (row kl handled by wave kl%8) ----
    float4 acc[QT];
#pragma unroll
    for (int q = 0; q < QT; ++q) acc[q] = make_float4(0.f, 0.f, 0.f, 0.f);

    const float* Vb = values + ((size_t)b * NK + kstart) * ND;
#pragma unroll 2
    for (int kl = wid; kl < range8; kl += 8) {
        uint4 u = *(const uint4*)&p_l[(size_t)kl * 8];   // 1 b128 = all 8 bf16 p's
        float pr0 = b2f_lo(u.x), pr1 = b2f_hi(u.x);
        float pr2 = b2f_lo(u.y), pr3 = b2f_hi(u.y);
        float pr4 = b2f_lo(u.z), pr5 = b2f_hi(u.z);
        float pr6 = b2f_lo(u.w), pr7 = b2f_hi(u.w);
        float4 v = *(const float4*)(Vb + (size_t)kl * ND + dl);  // coalesced 1KB
        acc[0].x = fmaf(pr0, v.x, acc[0].x); acc[0].y = fmaf(pr0, v.y, acc[0].y);
        acc[0].z = fmaf(pr0, v.z, acc[0].z); acc[0].w = fmaf(pr0, v.w, acc[0].w);
        acc[1].x = fmaf(pr1, v.x, acc[1].x); acc[1].y = fmaf(pr1, v.y, acc[1].y);
        acc[1].z = fmaf(pr1, v.z, acc[1].z); acc[1].w = fmaf(pr1, v.w, acc[1].w);
        acc[2].x = fmaf(pr2, v.x, acc[2].x); acc[2].y = fmaf(pr2, v.y, acc[2].y);
        acc[2].z = fmaf(pr2, v.z, acc[2].z); acc[2].w = fmaf(pr2, v.w, acc[2].w);
        acc[3].x = fmaf(pr3, v.x, acc[3].x); acc[3].y = fmaf(pr3, v.y, acc[3].y);
        acc[3].z = fmaf(pr3, v.z, acc[3].z); acc[3].w = fmaf(pr3, v.w, acc[3].w);
        acc[4].x = fmaf(pr4, v.x, acc[4].x); acc[4].y = fmaf(pr4, v.y, acc[4].y);
        acc[4].z = fmaf(pr4, v.z, acc[4].z); acc[4].w = fmaf(pr4, v.w, acc[4].w);
        acc[5].x = fmaf(pr5, v.x, acc[5].x); acc[5].y = fmaf(pr5, v.y, acc[5].y);
        acc[5].z = fmaf(pr5, v.z, acc[5].z); acc[5].w = fmaf(pr5, v.w, acc[5].w);
        acc[6].x = fmaf(pr6, v.x, acc[6].x); acc[6].y = fmaf(pr6, v.y, acc[6].y);
        acc[6].z = fmaf(pr6, v.z, acc[6].z); acc[6].w = fmaf(pr6, v.w, acc[6].w);
        acc[7].x = fmaf(pr7, v.x, acc[7].x); acc[7].y = fmaf(pr7, v.y, acc[7].y);
        acc[7].z = fmaf(pr7, v.z, acc[7].z); acc[7].w = fmaf(pr7, v.w, acc[7].w);
    }
    __syncthreads();                          // p-values dead -> reuse buf as scratch

    // ---- phase 3: tree-reduce partials across waves (8 -> 4 -> 2 -> 1) ----
    if (wid >= 4) {
        float* s = buf + (size_t)(wid - 4) * 2048;
#pragma unroll
        for (int q = 0; q < QT; ++q) *(float4*)(s + q * 256 + dl) = acc[q];
    }
    __syncthreads();
    if (wid < 4) {
        const float* s = buf + (size_t)wid * 2048;
#pragma unroll
        for (int q = 0; q < QT; ++q) {
            float4 r = *(const float4*)(s + q * 256 + dl);
            acc[q].x += r.x; acc[q].y += r.y; acc[q].z += r.z; acc[q].w += r.w;
        }
    }
    __syncthreads();
    if (wid >= 2 && wid < 4) {
        float* s = buf + (size_t)(wid - 2) * 2048;
#pragma unroll
        for (int q = 0; q < QT; ++q) *(float4*)(s + q * 256 + dl) = acc[q];
    }
    __syncthreads();
    if (wid < 2) {
        const float* s = buf + (size_t)wid * 2048;
#pragma unroll
        for (int q = 0; q < QT; ++q) {
            float4 r = *(const float4*)(s + q * 256 + dl);
            acc[q].x += r.x; acc[q].y += r.y; acc[q].z += r.z; acc[q].w += r.w;
        }
    }
    __syncthreads();
    if (wid == 1) {
#pragma unroll
        for (int q = 0; q < QT; ++q) *(float4*)(buf + q * 256 + dl) = acc[q];
    }
    __syncthreads();
    if (wid == 0) {
#pragma unroll
        for (int q = 0; q < QT; ++q) {
            float4 r = *(const float4*)(buf + q * 256 + dl);
            acc[q].x += r.x; acc[q].y += r.y; acc[q].z += r.z; acc[q].w += r.w;
            const size_t row4 = ((size_t)(b * NQ + q0 + q) * KSPLIT + sp);
            *(float4*)(po + row4 * ND + dl) = acc[q];
        }
        if (t < QT) {
            float l = 0.f;
#pragma unroll
            for (int i = 0; i < 8; ++i) l += red_l[t][i];
            pml[((size_t)(b * NQ + q0 + t) * KSPLIT + sp)] = l;
        }
    }
}

// ---------- kernel C: combine the four splits ----------
__global__ __launch_bounds__(256) void combine_kernel(
    const float* __restrict__ po, const float* __restrict__ pml,
    float* __restrict__ out)
{
    const int t = threadIdx.x;
    const int row = blockIdx.x * 4 + (t >> 6);
    const int dl = (t & 63) * 4;
    float l = 0.f;
#pragma unroll
    for (int s = 0; s < KSPLIT; ++s) l += pml[row * KSPLIT + s];
    float4 o = make_float4(0.f, 0.f, 0.f, 0.f);
#pragma unroll
    for (int s = 0; s < KSPLIT; ++s) {
        float4 p = *(const float4*)(po + ((size_t)row * KSPLIT + s) * ND + dl);
        o.x += p.x; o.y += p.y; o.z += p.z; o.w += p.w;
    }
    const float inv = 1.0f / l;
    o.x *= inv; o.y *= inv; o.z *= inv; o.w *= inv;
    *(float4*)(out + (size_t)row * ND + dl) = o;
}

extern "C" void kernel_launch(void* const* d_in, const int* in_sizes, int n_in,
                              void* d_out, int out_size, void* d_ws, size_t ws_size,
                              hipStream_t stream) {
    const float* queries   = (const float*)d_in[0];
    const float* keys      = (const float*)d_in[1];
    const float* values    = (const float*)d_in[2];
    const int* valid_lens  = (const int*)d_in[3];
    const float* Wq        = (const float*)d_in[4];
    const float* Wk        = (const float*)d_in[5];
    const float* wv        = (const float*)d_in[6];
    float* out = (float*)d_out;

    float* eq   = (float*)d_ws;                         // NB*NQ*NH      (0.5 MB)
    float4* ek4 = (float4*)(eq + (size_t)NB * NQ * NH); // NB*16*NK f4   (2 MB)
    float* po   = (float*)(ek4 + (size_t)NB * 16 * NK); // NB*NQ*4*ND    (8 MB)
    float* pml  = po + (size_t)NB * NQ * KSPLIT * ND;   // NB*NQ*4

    proj_kernel<<<(NB * NQ + NB * NK) / 16, 256, 0, stream>>>(queries, keys, Wq, Wk, eq, ek4);
    attn_part<<<NB * (NQ / QT) * KSPLIT, 512, 0, stream>>>(values, valid_lens, wv, eq, ek4, po, pml);
    combine_kernel<<<NB * NQ / 4, 256, 0, stream>>>(po, pml, out);
}